// Round 3
// baseline (196.717 us; speedup 1.0000x reference)
//
#include <hip/hip_runtime.h>
#include <hip/hip_bf16.h>
#include <stdint.h>

// Problem constants
#define BB      131072
#define D_IN    100
#define HN      50
#define TT      100
#define DT_C    0.01f
#define GAMMA_C 0.05f
#define I0_C    0.12f

// Packed-weight layout in d_ws (floats), in exact consumption order:
//   W0T [100][50]  at 0      (W0T[i][j] = W0[j][i])
//   b0  [50]       at 5000
//   W1  [50][50]   at 5050   (row-major, as input)
//   b1  [50]       at 7550
//   W2  [99][50]   at 7600   (row-major, as input)
//   b2  [99]       at 12550
// total 12649 floats = 50,596 bytes
#define PW_W0T 0
#define PW_B0  5000
#define PW_W1  5050
#define PW_B1  7550
#define PW_W2  7600
#define PW_B2  12550

__global__ void pack_kernel(const float* __restrict__ W0, const float* __restrict__ b0,
                            const float* __restrict__ W1, const float* __restrict__ b1,
                            const float* __restrict__ W2, const float* __restrict__ b2,
                            float* __restrict__ ws)
{
    const int gid = blockIdx.x * blockDim.x + threadIdx.x;
    const int gsz = gridDim.x * blockDim.x;
    for (int idx = gid; idx < 5000; idx += gsz) {           // transpose W0 [50][100] -> [100][50]
        int i = idx / 50, j = idx % 50;
        ws[PW_W0T + idx] = W0[j * 100 + i];
    }
    for (int idx = gid; idx < 50; idx += gsz)   ws[PW_B0 + idx] = b0[idx];
    for (int idx = gid; idx < 2500; idx += gsz) ws[PW_W1 + idx] = W1[idx];
    for (int idx = gid; idx < 50; idx += gsz)   ws[PW_B1 + idx] = b1[idx];
    for (int idx = gid; idx < 4950; idx += gsz) ws[PW_W2 + idx] = W2[idx];
    for (int idx = gid; idx < 99; idx += gsz)   ws[PW_B2 + idx] = b2[idx];
}

// 50-element dot with wave-uniform (scalar) weights. h must be a
// statically-indexed register array (fully unrolled).
__device__ __forceinline__ float dot50(const float* __restrict__ wrow, float bias,
                                       const float h[HN])
{
    float s0 = bias, s1 = 0.f, s2 = 0.f, s3 = 0.f;
    #pragma unroll
    for (int q = 0; q < 12; ++q) {
        s0 = fmaf(h[4 * q + 0], wrow[4 * q + 0], s0);
        s1 = fmaf(h[4 * q + 1], wrow[4 * q + 1], s1);
        s2 = fmaf(h[4 * q + 2], wrow[4 * q + 2], s2);
        s3 = fmaf(h[4 * q + 3], wrow[4 * q + 3], s3);
    }
    s0 = fmaf(h[48], wrow[48], s0);
    s1 = fmaf(h[49], wrow[49], s1);
    return (s0 + s2) + (s1 + s3);
}

__device__ __forceinline__ float euler_step(float I, float o)
{
    return I + DT_C * (o * I * (1.0f - I) - GAMMA_C * I);
}

__global__ __launch_bounds__(256, 2) void net_kernel(
    const float* __restrict__ x,
    const float* __restrict__ w,     // packed weights in d_ws
    float* __restrict__ out)
{
    const int b = blockIdx.x * 256 + threadIdx.x;

    // ---- Layer 0: acc[j] = b0[j] + sum_i x_i * W0T[i][j]. Weights scalar, x streamed ----
    float acc[HN];
    {
        const float* __restrict__ b0p = w + PW_B0;
        #pragma unroll
        for (int j = 0; j < HN; ++j) acc[j] = b0p[j];
    }
    const float4* __restrict__ xr = reinterpret_cast<const float4*>(x + (size_t)b * D_IN);
    #pragma unroll 1
    for (int i4 = 0; i4 < 25; ++i4) {
        float4 xv = xr[i4];
        const float* __restrict__ wr = w + PW_W0T + (i4 * 4) * HN;  // uniform
        #pragma unroll
        for (int r = 0; r < 4; ++r) {
            const float xi = (r == 0) ? xv.x : (r == 1) ? xv.y : (r == 2) ? xv.z : xv.w;
            const float* __restrict__ wrow = wr + r * HN;
            #pragma unroll
            for (int j = 0; j < HN; ++j)
                acc[j] = fmaf(xi, wrow[j], acc[j]);   // v_fma_f32 vdst, s, v, v
        }
    }

    float h0[HN];
    #pragma unroll
    for (int j = 0; j < HN; ++j) h0[j] = fmaxf(acc[j], 0.0f);

    // ---- Layer 1: h1[j] = relu(b1[j] + sum_i h0[i]*W1[j][i]). Fully unrolled ----
    float h1[HN];
    {
        const float* __restrict__ w1 = w + PW_W1;
        const float* __restrict__ b1p = w + PW_B1;
        #pragma unroll
        for (int j = 0; j < HN; ++j)
            h1[j] = fmaxf(dot50(w1 + j * HN, b1p[j], h0), 0.0f);
    }

    // ---- Layer 2 + Euler scan, output in 16-float (64 B/lane) register chunks ----
    const float* __restrict__ w2 = w + PW_W2;
    const float* __restrict__ b2p = w + PW_B2;
    float* __restrict__ orow = out + (size_t)b * TT;   // 400 B rows, 16 B aligned

    float cur = I0_C;
    float v[16];

    // chunk 0: I[0..15] (dots k = 0..14)
    v[0] = cur;
    #pragma unroll
    for (int t = 1; t < 16; ++t) {
        float o = dot50(w2 + (t - 1) * HN, b2p[t - 1], h1);
        cur = euler_step(cur, o);
        v[t] = cur;
    }
    {
        float4* o4 = reinterpret_cast<float4*>(orow);
        o4[0] = make_float4(v[0], v[1], v[2], v[3]);
        o4[1] = make_float4(v[4], v[5], v[6], v[7]);
        o4[2] = make_float4(v[8], v[9], v[10], v[11]);
        o4[3] = make_float4(v[12], v[13], v[14], v[15]);
    }

    // chunks 1..5: I[16c .. 16c+15] (dots k = 16c-1 .. 16c+14)
    #pragma unroll 1
    for (int c = 1; c < 6; ++c) {
        const float* __restrict__ wk = w2 + (16 * c - 1) * HN;  // uniform
        const float* __restrict__ bk = b2p + (16 * c - 1);
        #pragma unroll
        for (int t = 0; t < 16; ++t) {
            float o = dot50(wk + t * HN, bk[t], h1);
            cur = euler_step(cur, o);
            v[t] = cur;
        }
        float4* o4 = reinterpret_cast<float4*>(orow + 16 * c);
        o4[0] = make_float4(v[0], v[1], v[2], v[3]);
        o4[1] = make_float4(v[4], v[5], v[6], v[7]);
        o4[2] = make_float4(v[8], v[9], v[10], v[11]);
        o4[3] = make_float4(v[12], v[13], v[14], v[15]);
    }

    // tail: I[96..99] (dots k = 95..98)
    {
        float t0, t1, t2, t3;
        cur = euler_step(cur, dot50(w2 + 95 * HN, b2p[95], h1)); t0 = cur;
        cur = euler_step(cur, dot50(w2 + 96 * HN, b2p[96], h1)); t1 = cur;
        cur = euler_step(cur, dot50(w2 + 97 * HN, b2p[97], h1)); t2 = cur;
        cur = euler_step(cur, dot50(w2 + 98 * HN, b2p[98], h1)); t3 = cur;
        reinterpret_cast<float4*>(orow + 96)[0] = make_float4(t0, t1, t2, t3);
    }
}

extern "C" void kernel_launch(void* const* d_in, const int* in_sizes, int n_in,
                              void* d_out, int out_size, void* d_ws, size_t ws_size,
                              hipStream_t stream) {
    const float* x  = (const float*)d_in[0];
    const float* W0 = (const float*)d_in[1];
    const float* b0 = (const float*)d_in[2];
    const float* W1 = (const float*)d_in[3];
    const float* b1 = (const float*)d_in[4];
    const float* W2 = (const float*)d_in[5];
    const float* b2 = (const float*)d_in[6];
    float* out = (float*)d_out;
    float* ws  = (float*)d_ws;

    pack_kernel<<<dim3(64), dim3(256), 0, stream>>>(W0, b0, W1, b1, W2, b2, ws);
    net_kernel<<<dim3(BB / 256), dim3(256), 0, stream>>>(x, ws, out);
}